// Round 14
// baseline (152.812 us; speedup 1.0000x reference)
//
#include <hip/hip_runtime.h>
#include <math.h>

#define T_TOTAL 16384   // B*S
#define C_DIM   4096
#define E_DIM   64
#define K_TOP   8
#define S_SEQ   4096
#define B_BATCH 4

typedef short  short8 __attribute__((ext_vector_type(8)));
typedef float  f32x4  __attribute__((ext_vector_type(4)));

__device__ __forceinline__ unsigned short bf16_rte(float x) {
    unsigned u = __float_as_uint(x);
    return (unsigned short)((u + 0x7fffu + ((u >> 16) & 1u)) >> 16);
}
__device__ __forceinline__ float bf16_back(unsigned short h) {
    return __uint_as_float(((unsigned)h) << 16);
}

// ---- pack W into B-fragment layout, 3 bf16 split planes (r13 verbatim) ----
// wb[((s*128 + kt)*4 + n)*64 + l] = uint4 of 8 bf16:
//   elem i = split_s( W[n*16 + (l&15)][kt*32 + (l>>4)*8 + i] )
__global__ void pack_w_kernel(const float* __restrict__ w,
                              uint4* __restrict__ wb) {
    int gidx = blockIdx.x * 256 + threadIdx.x;   // [0, 98304)
    int l  = gidx & 63;
    int n  = (gidx >> 6) & 3;
    int kt = (gidx >> 8) & 127;
    int s  = gidx >> 15;                         // 0..2
    int e  = n * 16 + (l & 15);
    int kb = kt * 32 + (l >> 4) * 8;
    const float* src = w + (size_t)e * C_DIM + kb;
    unsigned short h[8];
#pragma unroll
    for (int i = 0; i < 8; ++i) {
        float v = src[i];
        unsigned short b1 = bf16_rte(v);
        if (s == 0) { h[i] = b1; continue; }
        float r = v - bf16_back(b1);             // exact (Sterbenz)
        unsigned short b2 = bf16_rte(r);
        if (s == 1) { h[i] = b2; continue; }
        float r2 = r - bf16_back(b2);            // exact
        h[i] = bf16_rte(r2);
    }
    uint4 o;
    o.x = (unsigned)h[0] | ((unsigned)h[1] << 16);
    o.y = (unsigned)h[2] | ((unsigned)h[3] << 16);
    o.z = (unsigned)h[4] | ((unsigned)h[5] << 16);
    o.w = (unsigned)h[6] | ((unsigned)h[7] << 16);
    wb[gidx] = o;
}

// one K=32 step: split x to 3 bf16 A-frags, 12 B-frag loads, 24 MFMAs (r13)
__device__ __forceinline__ void kstep(const uint4* __restrict__ wstep,
                                      const float xv[8], f32x4 accI[4]) {
    short8 A1, A2, A3;
#pragma unroll
    for (int i = 0; i < 8; ++i) {
        float v = xv[i];
        unsigned short h1 = bf16_rte(v);
        float r = v - bf16_back(h1);
        unsigned short h2 = bf16_rte(r);
        float r2 = r - bf16_back(h2);
        unsigned short h3 = bf16_rte(r2);
        A1[i] = (short)h1; A2[i] = (short)h2; A3[i] = (short)h3;
    }
    uint4 q[3][4];
#pragma unroll
    for (int s = 0; s < 3; ++s)
#pragma unroll
        for (int n = 0; n < 4; ++n)
            q[s][n] = wstep[s * 32768 + n * 64];
    union { uint4 u; short8 v; } cv;
#pragma unroll
    for (int n = 0; n < 4; ++n) {
        short8 B1, B2, B3;
        cv.u = q[0][n]; B1 = cv.v;
        cv.u = q[1][n]; B2 = cv.v;
        cv.u = q[2][n]; B3 = cv.v;
        f32x4 c = accI[n];
        c = __builtin_amdgcn_mfma_f32_16x16x32_bf16(A1, B1, c, 0, 0, 0);
        c = __builtin_amdgcn_mfma_f32_16x16x32_bf16(A1, B2, c, 0, 0, 0);
        c = __builtin_amdgcn_mfma_f32_16x16x32_bf16(A2, B1, c, 0, 0, 0);
        c = __builtin_amdgcn_mfma_f32_16x16x32_bf16(A1, B3, c, 0, 0, 0);
        c = __builtin_amdgcn_mfma_f32_16x16x32_bf16(A3, B1, c, 0, 0, 0);
        c = __builtin_amdgcn_mfma_f32_16x16x32_bf16(A2, B2, c, 0, 0, 0);
        accI[n] = c;
    }
}

// ---- fused gate: bf16x3 MFMA GEMM + verified top-8 epilogue ----
// 512 blocks x 512 threads (2 blocks/CU -> 16 waves/CU). Block = 32 tokens.
// Wave wv: M-tile mt = wv&1 (16 tokens), K-quarter kh = wv>>1 (1024 ch).
// No LDS/barriers in main loop. A-frag row = lane&15 (token),
// k = (lane>>4)*8+i; 2-deep named x prefetch. 256-ch chunk flushes and
// C/D-write indexing bit-identical to the r13 absmax=0 kernel; epilogue
// sums the 4 K-quarter slog planes ascending (r5-verified split-sum class).
__global__ __launch_bounds__(512, 2)
void gate_mfma_kernel(const float* __restrict__ x,
                      const uint4* __restrict__ wb,
                      const float* __restrict__ expert_bias,
                      float* __restrict__ out,
                      float* __restrict__ facc,
                      float* __restrict__ pacc) {
    const int tid  = threadIdx.x;
    const int lane = tid & 63;
    const int wv   = tid >> 6;        // 0..7
    const int mt   = wv & 1;
    const int kh   = wv >> 1;         // 0..3
    const int tok0 = blockIdx.x * 32;
    const int row  = lane & 15;
    const int g    = lane >> 4;

    __shared__ float slog[4][32][65];

    const float* xptr = x + (size_t)(tok0 + mt * 16 + row) * C_DIM
                          + kh * 1024 + g * 8;
    const uint4* wbl  = wb + lane + (size_t)(kh * 32) * 256;  // + t*256

    f32x4 accI[4], accO[4];
#pragma unroll
    for (int n = 0; n < 4; ++n)
#pragma unroll
        for (int j = 0; j < 4; ++j) { accI[n][j] = 0.0f; accO[n][j] = 0.0f; }

    // 2-deep x prefetch, named regs (even/odd)
    float4 ea0 = *(const float4*)(xptr);
    float4 ea1 = *(const float4*)(xptr + 4);
    float4 ob0 = *(const float4*)(xptr + 32);
    float4 ob1 = *(const float4*)(xptr + 36);

#pragma unroll 1
    for (int t = 0; t < 32; t += 2) {
        float xe[8] = {ea0.x, ea0.y, ea0.z, ea0.w, ea1.x, ea1.y, ea1.z, ea1.w};
        if (t + 2 < 32) {
            ea0 = *(const float4*)(xptr + (t + 2) * 32);
            ea1 = *(const float4*)(xptr + (t + 2) * 32 + 4);
        }
        kstep(wbl + (size_t)t * 256, xe, accI);

        float xo[8] = {ob0.x, ob0.y, ob0.z, ob0.w, ob1.x, ob1.y, ob1.z, ob1.w};
        if (t + 3 < 32) {
            ob0 = *(const float4*)(xptr + (t + 3) * 32);
            ob1 = *(const float4*)(xptr + (t + 3) * 32 + 4);
        }
        kstep(wbl + (size_t)(t + 1) * 256, xo, accI);

        if ((t & 7) == 6) {                      // flush every 8 steps = 256 ch
#pragma unroll
            for (int n = 0; n < 4; ++n)
#pragma unroll
                for (int j = 0; j < 4; ++j) {
                    accO[n][j] += accI[n][j]; accI[n][j] = 0.0f;
                }
        }
    }

    // write logits (r13 C/D map): slog[kh][token][expert]
#pragma unroll
    for (int n = 0; n < 4; ++n)
#pragma unroll
        for (int r = 0; r < 4; ++r)
            slog[kh][mt * 16 + g * 4 + r][n * 16 + row] = accO[n][r];
    __syncthreads();

    // ---- phase 2: verified top-8 butterfly; wave wv handles 4 tokens ----
    const float be = expert_bias[lane];
    const int   b  = tok0 / S_SEQ;               // uniform per block
    float f_local = 0.0f, p_local = 0.0f;

    for (int m = 0; m < 4; ++m) {
        const int tl = wv * 4 + m;
        const int tk = tok0 + tl;
        const float logit = slog[0][tl][lane] + slog[1][tl][lane]
                          + slog[2][tl][lane] + slog[3][tl][lane];
        const float sc = 1.0f / (1.0f + expf(-logit));   // sigmoid
        float ssum = sc;
#pragma unroll
        for (int off = 32; off >= 1; off >>= 1) ssum += __shfl_xor(ssum, off, 64);
        p_local += sc / (ssum + 1e-10f);

        float v = logit + be;
        float wsum = 0.0f, my_w = 0.0f;
        int   my_i = 0;
#pragma unroll
        for (int k = 0; k < K_TOP; ++k) {
            float rv = v;
            int   ri = lane;
#pragma unroll
            for (int off = 32; off >= 1; off >>= 1) {
                float ov = __shfl_xor(rv, off, 64);
                int   oi = __shfl_xor(ri, off, 64);
                if (ov > rv || (ov == rv && oi < ri)) { rv = ov; ri = oi; }
            }
            float wsc = __shfl(sc, ri, 64);      // winner's score (uniform)
            wsum += wsc;
            if (lane == k)  { my_i = ri; my_w = wsc; }
            if (lane == ri) { v = -INFINITY; f_local += 1.0f; }
        }
        if (lane < K_TOP) {
            out[(size_t)tk * K_TOP + lane] = (float)my_i;
            out[(size_t)T_TOTAL * K_TOP + (size_t)tk * K_TOP + lane] =
                my_w / (wsum + 1e-10f);
        }
    }

    atomicAdd(&facc[b * E_DIM + lane], f_local);
    atomicAdd(&pacc[b * E_DIM + lane], p_local);
}

// ---- tiny loss reduction: 4x64 f*p -> scalar ----
__global__ void loss_kernel(const float* __restrict__ facc,
                            const float* __restrict__ pacc,
                            float* __restrict__ out_loss) {
    const int tid = threadIdx.x;                 // 256 threads = B*E
    float f = facc[tid] * (1.0f / ((float)K_TOP * (float)S_SEQ));
    float p = pacc[tid] * (1.0f / (float)S_SEQ);
    float v = f * p;
#pragma unroll
    for (int off = 32; off >= 1; off >>= 1) v += __shfl_xor(v, off, 64);
    __shared__ float sred[4];
    if ((tid & 63) == 0) sred[tid >> 6] = v;
    __syncthreads();
    if (tid == 0) {
        float tot = sred[0] + sred[1] + sred[2] + sred[3];
        out_loss[0] = 0.001f * tot / (float)B_BATCH;
    }
}

extern "C" void kernel_launch(void* const* d_in, const int* in_sizes, int n_in,
                              void* d_out, int out_size, void* d_ws, size_t ws_size,
                              hipStream_t stream) {
    const float* x    = (const float*)d_in[0];   // [4,4096,4096] f32
    const float* w    = (const float*)d_in[1];   // [64,4096] f32
    const float* bias = (const float*)d_in[2];   // [64] f32
    float* out = (float*)d_out;                  // [131072 idx][131072 w][1 loss]

    float* facc = (float*)d_ws;                  // 256 floats
    float* pacc = facc + B_BATCH * E_DIM;        // 256 floats
    uint4* wb   = (uint4*)((char*)d_ws + 4096);  // 1.5 MB packed split-W

    // zero the f/p accumulators every call (atomics accumulate)
    hipMemsetAsync(d_ws, 0, 2048, stream);

    pack_w_kernel<<<384, 256, 0, stream>>>(w, wb);

    gate_mfma_kernel<<<512, 512, 0, stream>>>(x, wb, bias, out, facc, pacc);

    loss_kernel<<<1, 256, 0, stream>>>(facc, pacc, out + 2 * (size_t)T_TOTAL * K_TOP);
}

// Round 15
// 126.661 us; speedup vs baseline: 1.2065x; 1.2065x over previous
//
#include <hip/hip_runtime.h>
#include <math.h>

#define T_TOTAL 16384   // B*S
#define C_DIM   4096
#define E_DIM   64
#define K_TOP   8
#define S_SEQ   4096
#define B_BATCH 4

typedef short  short8 __attribute__((ext_vector_type(8)));
typedef float  f32x4  __attribute__((ext_vector_type(4)));

__device__ __forceinline__ unsigned short bf16_rte(float x) {
    unsigned u = __float_as_uint(x);
    return (unsigned short)((u + 0x7fffu + ((u >> 16) & 1u)) >> 16);
}
__device__ __forceinline__ float bf16_back(unsigned short h) {
    return __uint_as_float(((unsigned)h) << 16);
}

// ---- pack W into B-fragment layout, 3 bf16 split planes (r13 verbatim) ----
// wb[((s*128 + kt)*4 + n)*64 + l] = uint4 of 8 bf16:
//   elem i = split_s( W[n*16 + (l&15)][kt*32 + (l>>4)*8 + i] )
__global__ void pack_w_kernel(const float* __restrict__ w,
                              uint4* __restrict__ wb) {
    int gidx = blockIdx.x * 256 + threadIdx.x;   // [0, 98304)
    int l  = gidx & 63;
    int n  = (gidx >> 6) & 3;
    int kt = (gidx >> 8) & 127;
    int s  = gidx >> 15;                         // 0..2
    int e  = n * 16 + (l & 15);
    int kb = kt * 32 + (l >> 4) * 8;
    const float* src = w + (size_t)e * C_DIM + kb;
    unsigned short h[8];
#pragma unroll
    for (int i = 0; i < 8; ++i) {
        float v = src[i];
        unsigned short b1 = bf16_rte(v);
        if (s == 0) { h[i] = b1; continue; }
        float r = v - bf16_back(b1);             // exact (Sterbenz)
        unsigned short b2 = bf16_rte(r);
        if (s == 1) { h[i] = b2; continue; }
        float r2 = r - bf16_back(b2);            // exact
        h[i] = bf16_rte(r2);
    }
    uint4 o;
    o.x = (unsigned)h[0] | ((unsigned)h[1] << 16);
    o.y = (unsigned)h[2] | ((unsigned)h[3] << 16);
    o.z = (unsigned)h[4] | ((unsigned)h[5] << 16);
    o.w = (unsigned)h[6] | ((unsigned)h[7] << 16);
    wb[gidx] = o;
}

__device__ __forceinline__ void split3(const float xv[8],
                                       short8& A1, short8& A2, short8& A3) {
#pragma unroll
    for (int i = 0; i < 8; ++i) {
        float v = xv[i];
        unsigned short h1 = bf16_rte(v);
        float r = v - bf16_back(h1);
        unsigned short h2 = bf16_rte(r);
        float r2 = r - bf16_back(h2);
        unsigned short h3 = bf16_rte(r2);
        A1[i] = (short)h1; A2[i] = (short)h2; A3[i] = (short)h3;
    }
}

// one K=32 step for TWO 16-row M-tiles sharing the same 12 B-frags.
// Per-accumulator MFMA order identical to r13: A1B1,A1B2,A2B1,A1B3,A3B1,A2B2.
__device__ __forceinline__ void kstep2(const uint4* __restrict__ wstep,
                                       const float xa[8], const float xb[8],
                                       f32x4 accA[4], f32x4 accB[4]) {
    short8 a1, a2, a3, b1, b2, b3;
    split3(xa, a1, a2, a3);
    split3(xb, b1, b2, b3);
    uint4 q[3][4];
#pragma unroll
    for (int s = 0; s < 3; ++s)
#pragma unroll
        for (int n = 0; n < 4; ++n)
            q[s][n] = wstep[s * 32768 + n * 64];
    union { uint4 u; short8 v; } cv;
#pragma unroll
    for (int n = 0; n < 4; ++n) {
        short8 B1, B2, B3;
        cv.u = q[0][n]; B1 = cv.v;
        cv.u = q[1][n]; B2 = cv.v;
        cv.u = q[2][n]; B3 = cv.v;
        f32x4 cA = accA[n], cB = accB[n];
        cA = __builtin_amdgcn_mfma_f32_16x16x32_bf16(a1, B1, cA, 0, 0, 0);
        cB = __builtin_amdgcn_mfma_f32_16x16x32_bf16(b1, B1, cB, 0, 0, 0);
        cA = __builtin_amdgcn_mfma_f32_16x16x32_bf16(a1, B2, cA, 0, 0, 0);
        cB = __builtin_amdgcn_mfma_f32_16x16x32_bf16(b1, B2, cB, 0, 0, 0);
        cA = __builtin_amdgcn_mfma_f32_16x16x32_bf16(a2, B1, cA, 0, 0, 0);
        cB = __builtin_amdgcn_mfma_f32_16x16x32_bf16(b2, B1, cB, 0, 0, 0);
        cA = __builtin_amdgcn_mfma_f32_16x16x32_bf16(a1, B3, cA, 0, 0, 0);
        cB = __builtin_amdgcn_mfma_f32_16x16x32_bf16(b1, B3, cB, 0, 0, 0);
        cA = __builtin_amdgcn_mfma_f32_16x16x32_bf16(a3, B1, cA, 0, 0, 0);
        cB = __builtin_amdgcn_mfma_f32_16x16x32_bf16(b3, B1, cB, 0, 0, 0);
        cA = __builtin_amdgcn_mfma_f32_16x16x32_bf16(a2, B2, cA, 0, 0, 0);
        cB = __builtin_amdgcn_mfma_f32_16x16x32_bf16(b2, B2, cB, 0, 0, 0);
        accA[n] = cA; accB[n] = cB;
    }
}

#define XE(p, q) {p.x, p.y, p.z, p.w, q.x, q.y, q.z, q.w}

// ---- fused gate: bf16x3 MFMA GEMM, M=32/wave + verified top-8 epilogue ----
// 256 blocks x 512 threads. Block = 64 tokens. Wave wv: mt = wv&1 (32-token
// pair: M-tiles at mt*32 and mt*32+16), kh = wv>>1 (1024-ch quarter). Same
// 12 B-frags serve both M-tiles (halves W vecmem traffic vs r14). No LDS /
// barriers in main loop; 2-deep named x prefetch per tile; 256-ch flushes
// and per-accumulator MFMA order bit-class-identical to r13/r14 (absmax=0).
__global__ __launch_bounds__(512, 2)
void gate_mfma_kernel(const float* __restrict__ x,
                      const uint4* __restrict__ wb,
                      const float* __restrict__ expert_bias,
                      float* __restrict__ out,
                      float* __restrict__ facc,
                      float* __restrict__ pacc) {
    const int tid  = threadIdx.x;
    const int lane = tid & 63;
    const int wv   = tid >> 6;        // 0..7
    const int mt   = wv & 1;
    const int kh   = wv >> 1;         // 0..3
    const int tok0 = blockIdx.x * 64;
    const int row  = lane & 15;
    const int g    = lane >> 4;

    __shared__ float slog[4][64][65];

    const float* xpa = x + (size_t)(tok0 + mt * 32 + row) * C_DIM
                         + kh * 1024 + g * 8;
    const float* xpb = xpa + 16 * C_DIM;
    const uint4* wbl = wb + lane + (size_t)(kh * 32) * 256;  // + t*256

    f32x4 accIA[4], accOA[4], accIB[4], accOB[4];
#pragma unroll
    for (int n = 0; n < 4; ++n)
#pragma unroll
        for (int j = 0; j < 4; ++j) {
            accIA[n][j] = 0.0f; accOA[n][j] = 0.0f;
            accIB[n][j] = 0.0f; accOB[n][j] = 0.0f;
        }

    // 2-deep x prefetch per tile, named regs (even/odd)
    float4 eaA0 = *(const float4*)(xpa);
    float4 eaA1 = *(const float4*)(xpa + 4);
    float4 eaB0 = *(const float4*)(xpb);
    float4 eaB1 = *(const float4*)(xpb + 4);
    float4 obA0 = *(const float4*)(xpa + 32);
    float4 obA1 = *(const float4*)(xpa + 36);
    float4 obB0 = *(const float4*)(xpb + 32);
    float4 obB1 = *(const float4*)(xpb + 36);

#pragma unroll 1
    for (int t = 0; t < 32; t += 2) {
        {
            float xa[8] = XE(eaA0, eaA1);
            float xb[8] = XE(eaB0, eaB1);
            if (t + 2 < 32) {
                eaA0 = *(const float4*)(xpa + (t + 2) * 32);
                eaA1 = *(const float4*)(xpa + (t + 2) * 32 + 4);
                eaB0 = *(const float4*)(xpb + (t + 2) * 32);
                eaB1 = *(const float4*)(xpb + (t + 2) * 32 + 4);
            }
            kstep2(wbl + (size_t)t * 256, xa, xb, accIA, accIB);
        }
        {
            float xa[8] = XE(obA0, obA1);
            float xb[8] = XE(obB0, obB1);
            if (t + 3 < 32) {
                obA0 = *(const float4*)(xpa + (t + 3) * 32);
                obA1 = *(const float4*)(xpa + (t + 3) * 32 + 4);
                obB0 = *(const float4*)(xpb + (t + 3) * 32);
                obB1 = *(const float4*)(xpb + (t + 3) * 32 + 4);
            }
            kstep2(wbl + (size_t)(t + 1) * 256, xa, xb, accIA, accIB);
        }
        if ((t & 7) == 6) {                      // flush every 8 steps = 256 ch
#pragma unroll
            for (int n = 0; n < 4; ++n)
#pragma unroll
                for (int j = 0; j < 4; ++j) {
                    accOA[n][j] += accIA[n][j]; accIA[n][j] = 0.0f;
                    accOB[n][j] += accIB[n][j]; accIB[n][j] = 0.0f;
                }
        }
    }

    // write logits (r13 C/D map): slog[kh][token][expert]
#pragma unroll
    for (int n = 0; n < 4; ++n)
#pragma unroll
        for (int r = 0; r < 4; ++r) {
            slog[kh][mt * 32 + g * 4 + r][n * 16 + row]      = accOA[n][r];
            slog[kh][mt * 32 + 16 + g * 4 + r][n * 16 + row] = accOB[n][r];
        }
    __syncthreads();

    // ---- phase 2: verified top-8 butterfly; wave wv handles 8 tokens ----
    const float be = expert_bias[lane];
    const int   b  = tok0 / S_SEQ;               // uniform per block
    float f_local = 0.0f, p_local = 0.0f;

    for (int m = 0; m < 8; ++m) {
        const int tl = wv * 8 + m;
        const int tk = tok0 + tl;
        const float logit = slog[0][tl][lane] + slog[1][tl][lane]
                          + slog[2][tl][lane] + slog[3][tl][lane];
        const float sc = 1.0f / (1.0f + expf(-logit));   // sigmoid
        float ssum = sc;
#pragma unroll
        for (int off = 32; off >= 1; off >>= 1) ssum += __shfl_xor(ssum, off, 64);
        p_local += sc / (ssum + 1e-10f);

        float v = logit + be;
        float wsum = 0.0f, my_w = 0.0f;
        int   my_i = 0;
#pragma unroll
        for (int k = 0; k < K_TOP; ++k) {
            float rv = v;
            int   ri = lane;
#pragma unroll
            for (int off = 32; off >= 1; off >>= 1) {
                float ov = __shfl_xor(rv, off, 64);
                int   oi = __shfl_xor(ri, off, 64);
                if (ov > rv || (ov == rv && oi < ri)) { rv = ov; ri = oi; }
            }
            float wsc = __shfl(sc, ri, 64);      // winner's score (uniform)
            wsum += wsc;
            if (lane == k)  { my_i = ri; my_w = wsc; }
            if (lane == ri) { v = -INFINITY; f_local += 1.0f; }
        }
        if (lane < K_TOP) {
            out[(size_t)tk * K_TOP + lane] = (float)my_i;
            out[(size_t)T_TOTAL * K_TOP + (size_t)tk * K_TOP + lane] =
                my_w / (wsum + 1e-10f);
        }
    }

    atomicAdd(&facc[b * E_DIM + lane], f_local);
    atomicAdd(&pacc[b * E_DIM + lane], p_local);
}

// ---- tiny loss reduction: 4x64 f*p -> scalar ----
__global__ void loss_kernel(const float* __restrict__ facc,
                            const float* __restrict__ pacc,
                            float* __restrict__ out_loss) {
    const int tid = threadIdx.x;                 // 256 threads = B*E
    float f = facc[tid] * (1.0f / ((float)K_TOP * (float)S_SEQ));
    float p = pacc[tid] * (1.0f / (float)S_SEQ);
    float v = f * p;
#pragma unroll
    for (int off = 32; off >= 1; off >>= 1) v += __shfl_xor(v, off, 64);
    __shared__ float sred[4];
    if ((tid & 63) == 0) sred[tid >> 6] = v;
    __syncthreads();
    if (tid == 0) {
        float tot = sred[0] + sred[1] + sred[2] + sred[3];
        out_loss[0] = 0.001f * tot / (float)B_BATCH;
    }
}

extern "C" void kernel_launch(void* const* d_in, const int* in_sizes, int n_in,
                              void* d_out, int out_size, void* d_ws, size_t ws_size,
                              hipStream_t stream) {
    const float* x    = (const float*)d_in[0];   // [4,4096,4096] f32
    const float* w    = (const float*)d_in[1];   // [64,4096] f32
    const float* bias = (const float*)d_in[2];   // [64] f32
    float* out = (float*)d_out;                  // [131072 idx][131072 w][1 loss]

    float* facc = (float*)d_ws;                  // 256 floats
    float* pacc = facc + B_BATCH * E_DIM;        // 256 floats
    uint4* wb   = (uint4*)((char*)d_ws + 4096);  // 1.5 MB packed split-W

    // zero the f/p accumulators every call (atomics accumulate)
    hipMemsetAsync(d_ws, 0, 2048, stream);

    pack_w_kernel<<<384, 256, 0, stream>>>(w, wb);

    gate_mfma_kernel<<<256, 512, 0, stream>>>(x, wb, bias, out, facc, pacc);

    loss_kernel<<<1, 256, 0, stream>>>(facc, pacc, out + 2 * (size_t)T_TOTAL * K_TOP);
}